// Round 10
// baseline (1900.524 us; speedup 1.0000x reference)
//
#include <hip/hip_runtime.h>
#include <math.h>

#define SQ 1024  // S
#define EE 512   // E
#define NB 4     // B
#define NH 8     // H

// Optimization barrier: forces materialization (rounding) so the compiler
// cannot FMA-contract or reassociate across numpy's op boundaries.
__device__ __forceinline__ float sep(float x) {
  asm volatile("" : "+v"(x));
  return x;
}

// ================= LayerNorm, numpy-exact fp32 (np.mean pairwise) — FROZEN =================
__global__ __launch_bounds__(64) void ln_np(const float* __restrict__ x,
                                            const float* __restrict__ g,
                                            const float* __restrict__ b,
                                            float* __restrict__ y) {
  __shared__ float xs[EE];
  __shared__ float bc[2];
  long long t = blockIdx.x;
  int lane = threadIdx.x;
#pragma unroll
  for (int m = 0; m < 8; m++) xs[lane + 64 * m] = x[t * EE + lane + 64 * m];
  __syncthreads();
  int l = lane >> 3, a = lane & 7;
  float r = 0.f;
  if (lane < 32) {
    r = xs[l * 128 + a];
#pragma unroll
    for (int m = 1; m < 16; m++) r = r + xs[l * 128 + 8 * m + a];
  }
  r = r + __shfl_xor(r, 1);
  r = r + __shfl_xor(r, 2);
  r = r + __shfl_xor(r, 4);
  r = r + __shfl_xor(r, 8);
  r = r + __shfl_xor(r, 16);
  if (lane == 0) bc[0] = r / 512.0f;
  __syncthreads();
  float mean = bc[0];
  r = 0.f;
  if (lane < 32) {
#pragma unroll
    for (int m = 0; m < 16; m++) {
      float d = sep(xs[l * 128 + 8 * m + a] - mean);
      float s2 = sep(d * d);
      r = (m == 0) ? s2 : (r + s2);
    }
  }
  r = r + __shfl_xor(r, 1);
  r = r + __shfl_xor(r, 2);
  r = r + __shfl_xor(r, 4);
  r = r + __shfl_xor(r, 8);
  r = r + __shfl_xor(r, 16);
  if (lane == 0) bc[1] = r / 512.0f;
  __syncthreads();
  float var = bc[1];
  float rs = 1.0f / sqrtf(var + 1e-5f);
#pragma unroll
  for (int m = 0; m < 8; m++) {
    int i = lane + 64 * m;
    float d = sep(xs[i] - mean);
    float t1 = sep(d * rs);
    float t2 = sep(t1 * g[i]);
    y[t * EE + i] = t2 + b[i];
  }
}

// ================= distances — FROZEN =================
__global__ __launch_bounds__(256) void dist_np(const float* __restrict__ nq,
                                               const float* __restrict__ conv_w,
                                               const float* __restrict__ conv_b,
                                               float* __restrict__ dist) {
  int bh = blockIdx.x;
  int b = bh >> 3, h = bh & 7;
  float cb = conv_b[h];
  const float* W = conv_w + (long long)h * EE * 3;
  for (int s = threadIdx.x; s < SQ; s += 256) {
    float d = cb;
#pragma unroll
    for (int k = 0; k < 3; k++) {
      int t = s - 2 + k;
      if (t < 0) continue;
      const float* row = nq + ((long long)b * SQ + t) * EE;
      float acc = 0.f;
      for (int e = 0; e < EE; e++) acc = __builtin_fmaf(row[e], W[e * 3 + k], acc);
      d = sep(d + acc);
    }
    dist[(long long)bh * SQ + s] = (float)tanh((double)d);
  }
}

// ================= fp32 tiled NT-GEMM — FROZEN (R7 gemm_nt, byte-identical) =================
__device__ __forceinline__ float gelu_exact(float x) {
  return 0.5f * x * (1.f + erff(x / 1.41421356237309504880f));
}

template <int ACT, int SPLITK>
__global__ __launch_bounds__(256) void gemm_nt(const float* __restrict__ A, int lda, long long sA,
                                               const float* __restrict__ B, int ldb, long long sB,
                                               const float* __restrict__ bias,
                                               const float* __restrict__ Res,
                                               float* __restrict__ C, int ldc, long long sC,
                                               int K, float alpha) {
  __shared__ float As[16][68];
  __shared__ float Bs[16][68];
  int z = blockIdx.z;
  A += (long long)z * sA;
  B += (long long)z * sB;
  C += (long long)z * sC;
  int m0 = blockIdx.y * 64, n0 = blockIdx.x * 64;
  int tid = threadIdx.x;
  int lr = tid >> 2, lc = tid & 3;
  int tx = tid & 15, ty = tid >> 4;
  float acc[4][4] = {};
  float acc2[4][4] = {};
  const float* Arow = A + (long long)(m0 + lr) * lda + lc * 4;
  const float* Brow = B + (long long)(n0 + lr) * ldb + lc * 4;
  for (int k0 = 0; k0 < K; k0 += 16) {
    float4 a4 = *(const float4*)(Arow + k0);
    float4 b4 = *(const float4*)(Brow + k0);
    __syncthreads();
    As[lc * 4 + 0][lr] = a4.x; As[lc * 4 + 1][lr] = a4.y;
    As[lc * 4 + 2][lr] = a4.z; As[lc * 4 + 3][lr] = a4.w;
    Bs[lc * 4 + 0][lr] = b4.x; Bs[lc * 4 + 1][lr] = b4.y;
    Bs[lc * 4 + 2][lr] = b4.z; Bs[lc * 4 + 3][lr] = b4.w;
    __syncthreads();
    float(*tgt)[4] = (SPLITK > 0 && k0 >= SPLITK) ? acc2 : acc;
#pragma unroll
    for (int kk = 0; kk < 16; kk++) {
      float4 av = *(const float4*)&As[kk][ty * 4];
      float4 bv = *(const float4*)&Bs[kk][tx * 4];
      float a[4] = {av.x, av.y, av.z, av.w};
      float bb[4] = {bv.x, bv.y, bv.z, bv.w};
#pragma unroll
      for (int i = 0; i < 4; i++)
#pragma unroll
        for (int j = 0; j < 4; j++) tgt[i][j] += a[i] * bb[j];
    }
  }
  if (SPLITK > 0) {
#pragma unroll
    for (int i = 0; i < 4; i++)
#pragma unroll
      for (int j = 0; j < 4; j++) acc[i][j] = sep(acc[i][j]) + acc2[i][j];
  }
  float4 bias4 = make_float4(0.f, 0.f, 0.f, 0.f);
  if (ACT != 2 && bias) bias4 = *(const float4*)(bias + n0 + tx * 4);
#pragma unroll
  for (int i = 0; i < 4; i++) {
    int row = m0 + ty * 4 + i;
    float o[4];
    if (ACT == 2) {
#pragma unroll
      for (int j = 0; j < 4; j++) o[j] = acc[i][j] / alpha;
    } else {
      o[0] = sep(acc[i][0] * alpha) + bias4.x;
      o[1] = sep(acc[i][1] * alpha) + bias4.y;
      o[2] = sep(acc[i][2] * alpha) + bias4.z;
      o[3] = sep(acc[i][3] * alpha) + bias4.w;
    }
    if (ACT == 1) {
#pragma unroll
      for (int j = 0; j < 4; j++) o[j] = gelu_exact(o[j]);
    }
    if (Res) {
      float4 r4 = *(const float4*)(Res + (long long)row * ldc + n0 + tx * 4);
      o[0] = sep(o[0]) + r4.x; o[1] = sep(o[1]) + r4.y;
      o[2] = sep(o[2]) + r4.z; o[3] = sep(o[3]) + r4.w;
    }
    *(float4*)(C + (long long)row * ldc + n0 + tx * 4) = make_float4(o[0], o[1], o[2], o[3]);
  }
}

// ================= gated row sums: np.sum pairwise(1024) — FROZEN =================
__global__ __launch_bounds__(64) void rowsum_np(const float* __restrict__ scores,
                                                const float* __restrict__ dist,
                                                float* __restrict__ invrs) {
  __shared__ float wsm[SQ];
  int i = blockIdx.x;
  int z = blockIdx.y;
  int b = z >> 3;
  const float* srow = scores + ((long long)b * SQ + i) * SQ;
  const float* dz = dist + (long long)z * SQ;
  float di = dz[i];
  int lane = threadIdx.x;
#pragma unroll
  for (int m = 0; m < 16; m++) {
    int j = lane + 64 * m;
    float e = (float)exp((double)(dz[j] - di));
    float gg = 1.f / (1.f + e);
    wsm[j] = srow[j] * gg;
  }
  __syncthreads();
  int l = lane >> 3, a = lane & 7;
  float r = wsm[l * 128 + a];
#pragma unroll
  for (int m = 1; m < 16; m++) r = r + wsm[l * 128 + 8 * m + a];
  r = r + __shfl_xor(r, 1);
  r = r + __shfl_xor(r, 2);
  r = r + __shfl_xor(r, 4);
  r = r + __shfl_xor(r, 8);
  r = r + __shfl_xor(r, 16);
  r = r + __shfl_xor(r, 32);
  if (lane == 0) invrs[(long long)z * SQ + i] = 1.f / (r + 1e-12f);
}

// ================= ctx GEMM wide-N: R7 ctx_gemm with n-loop folded in =================
// Identical staging expressions, thread mapping, and per-element k-ascending
// FMA chains as R7's ctx_gemm; the only change is that one block now covers
// all 8 n-chunks (N=512) reusing the staged A-tile, so the gate expf staging
// and score loads happen once instead of 8x. Bit-identical output.
__global__ __launch_bounds__(256) void ctx_gemm_w(const float* __restrict__ scores,
                                                  const float* __restrict__ dist,
                                                  const float* __restrict__ invrs,
                                                  const float* __restrict__ qkv,
                                                  float* __restrict__ ctx) {
  __shared__ float As[16][68];
  __shared__ float Bs[16][520];  // 512 cols + 8 pad (keeps rows 16B-aligned)
  int z = blockIdx.y, b = z >> 3, h = z & 7;
  const float* A = scores + (long long)b * SQ * SQ;
  const float* V = qkv + (long long)b * SQ * (3 * EE) + 2 * EE;
  float* C = ctx + (long long)b * SQ * (NH * EE) + h * EE;
  const float* dz = dist + (long long)z * SQ;
  int m0 = blockIdx.x * 64;
  int tid = threadIdx.x;
  int lr = tid >> 2, lc = tid & 3;
  int bk = tid >> 4, bc = tid & 15;
  int tx = tid & 15, ty = tid >> 4;
  int arow = m0 + lr;
  float di = dz[arow];
  float inv = invrs[(long long)z * SQ + arow];
  float acc[8][4][4] = {};
  for (int k0 = 0; k0 < SQ; k0 += 16) {
    float4 s4 = *(const float4*)(A + (long long)arow * SQ + k0 + lc * 4);
    float g0 = 1.f / (1.f + expf(dz[k0 + lc * 4 + 0] - di));
    float g1 = 1.f / (1.f + expf(dz[k0 + lc * 4 + 1] - di));
    float g2 = 1.f / (1.f + expf(dz[k0 + lc * 4 + 2] - di));
    float g3 = 1.f / (1.f + expf(dz[k0 + lc * 4 + 3] - di));
    float4 v4[8];
#pragma unroll
    for (int nc = 0; nc < 8; nc++)
      v4[nc] = *(const float4*)(V + (long long)(k0 + bk) * (3 * EE) + nc * 64 + bc * 4);
    __syncthreads();
    As[lc * 4 + 0][lr] = (s4.x * g0) * inv;
    As[lc * 4 + 1][lr] = (s4.y * g1) * inv;
    As[lc * 4 + 2][lr] = (s4.z * g2) * inv;
    As[lc * 4 + 3][lr] = (s4.w * g3) * inv;
#pragma unroll
    for (int nc = 0; nc < 8; nc++)
      *(float4*)&Bs[bk][nc * 64 + bc * 4] = v4[nc];
    __syncthreads();
#pragma unroll
    for (int kk = 0; kk < 16; kk++) {
      float4 av = *(const float4*)&As[kk][ty * 4];
      float a[4] = {av.x, av.y, av.z, av.w};
#pragma unroll
      for (int nc = 0; nc < 8; nc++) {
        float4 bv = *(const float4*)&Bs[kk][nc * 64 + tx * 4];
        float bb[4] = {bv.x, bv.y, bv.z, bv.w};
#pragma unroll
        for (int i = 0; i < 4; i++)
#pragma unroll
          for (int j = 0; j < 4; j++) acc[nc][i][j] += a[i] * bb[j];
      }
    }
  }
#pragma unroll
  for (int i = 0; i < 4; i++) {
    int row = m0 + ty * 4 + i;
#pragma unroll
    for (int nc = 0; nc < 8; nc++) {
      *(float4*)(C + (long long)row * (NH * EE) + nc * 64 + tx * 4) =
          make_float4(acc[nc][i][0], acc[nc][i][1], acc[nc][i][2], acc[nc][i][3]);
    }
  }
}

extern "C" void kernel_launch(void* const* d_in, const int* in_sizes, int n_in,
                              void* d_out, int out_size, void* d_ws, size_t ws_size,
                              hipStream_t stream) {
  const float* query     = (const float*)d_in[0];
  const float* ln1_g     = (const float*)d_in[1];
  const float* ln1_b     = (const float*)d_in[2];
  const float* in_proj_w = (const float*)d_in[3];
  const float* in_proj_b = (const float*)d_in[4];
  const float* out_w     = (const float*)d_in[5];
  const float* out_b     = (const float*)d_in[6];
  const float* conv_w    = (const float*)d_in[7];
  const float* conv_b    = (const float*)d_in[8];
  const float* ln2_g     = (const float*)d_in[9];
  const float* ln2_b     = (const float*)d_in[10];
  const float* mlp_w1    = (const float*)d_in[11];
  const float* mlp_b1    = (const float*)d_in[12];
  const float* mlp_w2    = (const float*)d_in[13];
  const float* mlp_b2    = (const float*)d_in[14];
  float* out = (float*)d_out;
  char* ws = (char*)d_ws;

  // R7-exact layout: peak 112.25 MiB (proven safe in R1/R7)
  float* nq     = (float*)(ws + 0);                      // 8 MiB
  float* qkv    = (float*)(ws + (8ull << 20));           // 24 MiB
  float* dist   = (float*)(ws + (32ull << 20));          // 128 KiB
  float* invrs  = (float*)(ws + (32ull << 20) + 131072); // 128 KiB
  float* scores = (float*)(ws + (32ull << 20) + 262144); // 16 MiB
  float* ctx    = (float*)(ws + (48ull << 20) + 262144); // 64 MiB -> 112.25 MiB
  float* ln2out = scores;                                // reuse
  float* hbuf   = nq;                                    // reuse nq+qkv (32 MiB)

  // 1. LN1 (frozen)
  ln_np<<<dim3(NB * SQ), 64, 0, stream>>>(query, ln1_g, ln1_b, nq);
  // 2. distances (frozen)
  dist_np<<<dim3(NB * NH), 256, 0, stream>>>(nq, conv_w, conv_b, dist);
  // 3. qkv (sgemm KC=384, bit-identical chain)  M=4096 N=1536 K=512
  gemm_nt<0, 384><<<dim3(24, 64, 1), 256, 0, stream>>>(nq, EE, 0, in_proj_w, EE, 0,
                                                       in_proj_b, nullptr, qkv, 3 * EE, 0, EE, 1.f);
  // 4. scores (frozen chain + true division)  M=N=1024 K=512, batched B
  gemm_nt<2, 384><<<dim3(16, 16, NB), 256, 0, stream>>>(
      qkv, 3 * EE, (long long)SQ * 3 * EE, qkv + EE, 3 * EE, (long long)SQ * 3 * EE,
      nullptr, nullptr, scores, SQ, (long long)SQ * SQ, EE, sqrtf(512.0f));
  // 5. gated row sums (frozen)
  rowsum_np<<<dim3(SQ, NB * NH), 64, 0, stream>>>(scores, dist, invrs);
  // 6. ctx wide-N (batched over b,h)  M=1024 N=512 K=1024
  ctx_gemm_w<<<dim3(16, NB * NH), 256, 0, stream>>>(scores, dist, invrs, qkv, ctx);
  // 7. attn_out + residual  M=4096 N=512 K=4096
  gemm_nt<0, 0><<<dim3(8, 64, 1), 256, 0, stream>>>(ctx, NH * EE, 0, out_w, NH * EE, 0,
                                                    out_b, query, out, EE, 0, NH * EE, 1.f);
  // 8. LN2
  ln_np<<<dim3(NB * SQ), 64, 0, stream>>>(out, ln2_g, ln2_b, ln2out);
  // 9. MLP1 + gelu  M=4096 N=2048 K=512
  gemm_nt<1, 0><<<dim3(32, 64, 1), 256, 0, stream>>>(ln2out, EE, 0, mlp_w1, EE, 0,
                                                     mlp_b1, nullptr, hbuf, 4 * EE, 0, EE, 1.f);
  // 10. MLP2 + residual  M=4096 N=512 K=2048
  gemm_nt<0, 0><<<dim3(8, 64, 1), 256, 0, stream>>>(hbuf, 4 * EE, 0, mlp_w2, 4 * EE, 0,
                                                    mlp_b2, out, out, EE, 0, 4 * EE, 1.f);
}

// Round 11
// 1522.329 us; speedup vs baseline: 1.2484x; 1.2484x over previous
//
#include <hip/hip_runtime.h>
#include <math.h>

#define SQ 1024  // S
#define EE 512   // E
#define NB 4     // B
#define NH 8     // H

// Optimization barrier: forces materialization (rounding) so the compiler
// cannot FMA-contract or reassociate across numpy's op boundaries.
__device__ __forceinline__ float sep(float x) {
  asm volatile("" : "+v"(x));
  return x;
}

// ================= LayerNorm, numpy-exact fp32 (np.mean pairwise) — FROZEN =================
__global__ __launch_bounds__(64) void ln_np(const float* __restrict__ x,
                                            const float* __restrict__ g,
                                            const float* __restrict__ b,
                                            float* __restrict__ y) {
  __shared__ float xs[EE];
  __shared__ float bc[2];
  long long t = blockIdx.x;
  int lane = threadIdx.x;
#pragma unroll
  for (int m = 0; m < 8; m++) xs[lane + 64 * m] = x[t * EE + lane + 64 * m];
  __syncthreads();
  int l = lane >> 3, a = lane & 7;
  float r = 0.f;
  if (lane < 32) {
    r = xs[l * 128 + a];
#pragma unroll
    for (int m = 1; m < 16; m++) r = r + xs[l * 128 + 8 * m + a];
  }
  r = r + __shfl_xor(r, 1);
  r = r + __shfl_xor(r, 2);
  r = r + __shfl_xor(r, 4);
  r = r + __shfl_xor(r, 8);
  r = r + __shfl_xor(r, 16);
  if (lane == 0) bc[0] = r / 512.0f;
  __syncthreads();
  float mean = bc[0];
  r = 0.f;
  if (lane < 32) {
#pragma unroll
    for (int m = 0; m < 16; m++) {
      float d = sep(xs[l * 128 + 8 * m + a] - mean);
      float s2 = sep(d * d);
      r = (m == 0) ? s2 : (r + s2);
    }
  }
  r = r + __shfl_xor(r, 1);
  r = r + __shfl_xor(r, 2);
  r = r + __shfl_xor(r, 4);
  r = r + __shfl_xor(r, 8);
  r = r + __shfl_xor(r, 16);
  if (lane == 0) bc[1] = r / 512.0f;
  __syncthreads();
  float var = bc[1];
  float rs = 1.0f / sqrtf(var + 1e-5f);
#pragma unroll
  for (int m = 0; m < 8; m++) {
    int i = lane + 64 * m;
    float d = sep(xs[i] - mean);
    float t1 = sep(d * rs);
    float t2 = sep(t1 * g[i]);
    y[t * EE + i] = t2 + b[i];
  }
}

// ================= distances — FROZEN =================
__global__ __launch_bounds__(256) void dist_np(const float* __restrict__ nq,
                                               const float* __restrict__ conv_w,
                                               const float* __restrict__ conv_b,
                                               float* __restrict__ dist) {
  int bh = blockIdx.x;
  int b = bh >> 3, h = bh & 7;
  float cb = conv_b[h];
  const float* W = conv_w + (long long)h * EE * 3;
  for (int s = threadIdx.x; s < SQ; s += 256) {
    float d = cb;
#pragma unroll
    for (int k = 0; k < 3; k++) {
      int t = s - 2 + k;
      if (t < 0) continue;
      const float* row = nq + ((long long)b * SQ + t) * EE;
      float acc = 0.f;
      for (int e = 0; e < EE; e++) acc = __builtin_fmaf(row[e], W[e * 3 + k], acc);
      d = sep(d + acc);
    }
    dist[(long long)bh * SQ + s] = (float)tanh((double)d);
  }
}

// ================= fp32 tiled NT-GEMM — FROZEN (R7 gemm_nt, byte-identical) =================
__device__ __forceinline__ float gelu_exact(float x) {
  return 0.5f * x * (1.f + erff(x / 1.41421356237309504880f));
}

template <int ACT, int SPLITK>
__global__ __launch_bounds__(256) void gemm_nt(const float* __restrict__ A, int lda, long long sA,
                                               const float* __restrict__ B, int ldb, long long sB,
                                               const float* __restrict__ bias,
                                               const float* __restrict__ Res,
                                               float* __restrict__ C, int ldc, long long sC,
                                               int K, float alpha) {
  __shared__ float As[16][68];
  __shared__ float Bs[16][68];
  int z = blockIdx.z;
  A += (long long)z * sA;
  B += (long long)z * sB;
  C += (long long)z * sC;
  int m0 = blockIdx.y * 64, n0 = blockIdx.x * 64;
  int tid = threadIdx.x;
  int lr = tid >> 2, lc = tid & 3;
  int tx = tid & 15, ty = tid >> 4;
  float acc[4][4] = {};
  float acc2[4][4] = {};
  const float* Arow = A + (long long)(m0 + lr) * lda + lc * 4;
  const float* Brow = B + (long long)(n0 + lr) * ldb + lc * 4;
  for (int k0 = 0; k0 < K; k0 += 16) {
    float4 a4 = *(const float4*)(Arow + k0);
    float4 b4 = *(const float4*)(Brow + k0);
    __syncthreads();
    As[lc * 4 + 0][lr] = a4.x; As[lc * 4 + 1][lr] = a4.y;
    As[lc * 4 + 2][lr] = a4.z; As[lc * 4 + 3][lr] = a4.w;
    Bs[lc * 4 + 0][lr] = b4.x; Bs[lc * 4 + 1][lr] = b4.y;
    Bs[lc * 4 + 2][lr] = b4.z; Bs[lc * 4 + 3][lr] = b4.w;
    __syncthreads();
    float(*tgt)[4] = (SPLITK > 0 && k0 >= SPLITK) ? acc2 : acc;
#pragma unroll
    for (int kk = 0; kk < 16; kk++) {
      float4 av = *(const float4*)&As[kk][ty * 4];
      float4 bv = *(const float4*)&Bs[kk][tx * 4];
      float a[4] = {av.x, av.y, av.z, av.w};
      float bb[4] = {bv.x, bv.y, bv.z, bv.w};
#pragma unroll
      for (int i = 0; i < 4; i++)
#pragma unroll
        for (int j = 0; j < 4; j++) tgt[i][j] += a[i] * bb[j];
    }
  }
  if (SPLITK > 0) {
#pragma unroll
    for (int i = 0; i < 4; i++)
#pragma unroll
      for (int j = 0; j < 4; j++) acc[i][j] = sep(acc[i][j]) + acc2[i][j];
  }
  float4 bias4 = make_float4(0.f, 0.f, 0.f, 0.f);
  if (ACT != 2 && bias) bias4 = *(const float4*)(bias + n0 + tx * 4);
#pragma unroll
  for (int i = 0; i < 4; i++) {
    int row = m0 + ty * 4 + i;
    float o[4];
    if (ACT == 2) {
#pragma unroll
      for (int j = 0; j < 4; j++) o[j] = acc[i][j] / alpha;
    } else {
      o[0] = sep(acc[i][0] * alpha) + bias4.x;
      o[1] = sep(acc[i][1] * alpha) + bias4.y;
      o[2] = sep(acc[i][2] * alpha) + bias4.z;
      o[3] = sep(acc[i][3] * alpha) + bias4.w;
    }
    if (ACT == 1) {
#pragma unroll
      for (int j = 0; j < 4; j++) o[j] = gelu_exact(o[j]);
    }
    if (Res) {
      float4 r4 = *(const float4*)(Res + (long long)row * ldc + n0 + tx * 4);
      o[0] = sep(o[0]) + r4.x; o[1] = sep(o[1]) + r4.y;
      o[2] = sep(o[2]) + r4.z; o[3] = sep(o[3]) + r4.w;
    }
    *(float4*)(C + (long long)row * ldc + n0 + tx * 4) = make_float4(o[0], o[1], o[2], o[3]);
  }
}

// ================= gated row sums: np.sum pairwise(1024) — FROZEN =================
__global__ __launch_bounds__(64) void rowsum_np(const float* __restrict__ scores,
                                                const float* __restrict__ dist,
                                                float* __restrict__ invrs) {
  __shared__ float wsm[SQ];
  int i = blockIdx.x;
  int z = blockIdx.y;
  int b = z >> 3;
  const float* srow = scores + ((long long)b * SQ + i) * SQ;
  const float* dz = dist + (long long)z * SQ;
  float di = dz[i];
  int lane = threadIdx.x;
#pragma unroll
  for (int m = 0; m < 16; m++) {
    int j = lane + 64 * m;
    float e = (float)exp((double)(dz[j] - di));
    float gg = 1.f / (1.f + e);
    wsm[j] = srow[j] * gg;
  }
  __syncthreads();
  int l = lane >> 3, a = lane & 7;
  float r = wsm[l * 128 + a];
#pragma unroll
  for (int m = 1; m < 16; m++) r = r + wsm[l * 128 + 8 * m + a];
  r = r + __shfl_xor(r, 1);
  r = r + __shfl_xor(r, 2);
  r = r + __shfl_xor(r, 4);
  r = r + __shfl_xor(r, 8);
  r = r + __shfl_xor(r, 16);
  r = r + __shfl_xor(r, 32);
  if (lane == 0) invrs[(long long)z * SQ + i] = 1.f / (r + 1e-12f);
}

// ================= ctx GEMM wide-N (nc=4): R7 chain, 4 n-chunks per block =================
// Same staging expressions and per-element k-ascending FMA chains as R7/R10;
// one block covers 4 n-chunks (256 cols), grid 2x16x32 = 1024 blocks (4/CU).
__global__ __launch_bounds__(256) void ctx_gemm_w(const float* __restrict__ scores,
                                                  const float* __restrict__ dist,
                                                  const float* __restrict__ invrs,
                                                  const float* __restrict__ qkv,
                                                  float* __restrict__ ctx) {
  __shared__ float As[16][68];
  __shared__ float Bs[16][264];  // 256 cols + 8 pad
  int z = blockIdx.z, b = z >> 3, h = z & 7;
  const float* A = scores + (long long)b * SQ * SQ;
  const float* V = qkv + (long long)b * SQ * (3 * EE) + 2 * EE;
  float* C = ctx + (long long)b * SQ * (NH * EE) + h * EE;
  const float* dz = dist + (long long)z * SQ;
  int m0 = blockIdx.y * 64;
  int n0 = blockIdx.x * 256;
  int tid = threadIdx.x;
  int lr = tid >> 2, lc = tid & 3;
  int bk = tid >> 4, bc = tid & 15;
  int tx = tid & 15, ty = tid >> 4;
  int arow = m0 + lr;
  float di = dz[arow];
  float inv = invrs[(long long)z * SQ + arow];
  float acc[4][4][4] = {};
  for (int k0 = 0; k0 < SQ; k0 += 16) {
    float4 s4 = *(const float4*)(A + (long long)arow * SQ + k0 + lc * 4);
    float g0 = 1.f / (1.f + expf(dz[k0 + lc * 4 + 0] - di));
    float g1 = 1.f / (1.f + expf(dz[k0 + lc * 4 + 1] - di));
    float g2 = 1.f / (1.f + expf(dz[k0 + lc * 4 + 2] - di));
    float g3 = 1.f / (1.f + expf(dz[k0 + lc * 4 + 3] - di));
    float4 v4[4];
#pragma unroll
    for (int nc = 0; nc < 4; nc++)
      v4[nc] = *(const float4*)(V + (long long)(k0 + bk) * (3 * EE) + n0 + nc * 64 + bc * 4);
    __syncthreads();
    As[lc * 4 + 0][lr] = (s4.x * g0) * inv;
    As[lc * 4 + 1][lr] = (s4.y * g1) * inv;
    As[lc * 4 + 2][lr] = (s4.z * g2) * inv;
    As[lc * 4 + 3][lr] = (s4.w * g3) * inv;
#pragma unroll
    for (int nc = 0; nc < 4; nc++)
      *(float4*)&Bs[bk][nc * 64 + bc * 4] = v4[nc];
    __syncthreads();
#pragma unroll
    for (int kk = 0; kk < 16; kk++) {
      float4 av = *(const float4*)&As[kk][ty * 4];
      float a[4] = {av.x, av.y, av.z, av.w};
#pragma unroll
      for (int nc = 0; nc < 4; nc++) {
        float4 bv = *(const float4*)&Bs[kk][nc * 64 + tx * 4];
        float bb[4] = {bv.x, bv.y, bv.z, bv.w};
#pragma unroll
        for (int i = 0; i < 4; i++)
#pragma unroll
          for (int j = 0; j < 4; j++) acc[nc][i][j] += a[i] * bb[j];
      }
    }
  }
#pragma unroll
  for (int i = 0; i < 4; i++) {
    int row = m0 + ty * 4 + i;
#pragma unroll
    for (int nc = 0; nc < 4; nc++) {
      *(float4*)(C + (long long)row * (NH * EE) + n0 + nc * 64 + tx * 4) =
          make_float4(acc[nc][i][0], acc[nc][i][1], acc[nc][i][2], acc[nc][i][3]);
    }
  }
}

extern "C" void kernel_launch(void* const* d_in, const int* in_sizes, int n_in,
                              void* d_out, int out_size, void* d_ws, size_t ws_size,
                              hipStream_t stream) {
  const float* query     = (const float*)d_in[0];
  const float* ln1_g     = (const float*)d_in[1];
  const float* ln1_b     = (const float*)d_in[2];
  const float* in_proj_w = (const float*)d_in[3];
  const float* in_proj_b = (const float*)d_in[4];
  const float* out_w     = (const float*)d_in[5];
  const float* out_b     = (const float*)d_in[6];
  const float* conv_w    = (const float*)d_in[7];
  const float* conv_b    = (const float*)d_in[8];
  const float* ln2_g     = (const float*)d_in[9];
  const float* ln2_b     = (const float*)d_in[10];
  const float* mlp_w1    = (const float*)d_in[11];
  const float* mlp_b1    = (const float*)d_in[12];
  const float* mlp_w2    = (const float*)d_in[13];
  const float* mlp_b2    = (const float*)d_in[14];
  float* out = (float*)d_out;
  char* ws = (char*)d_ws;

  // R7-exact layout: peak 112.25 MiB (proven safe in R1/R7/R10)
  float* nq     = (float*)(ws + 0);                      // 8 MiB
  float* qkv    = (float*)(ws + (8ull << 20));           // 24 MiB
  float* dist   = (float*)(ws + (32ull << 20));          // 128 KiB
  float* invrs  = (float*)(ws + (32ull << 20) + 131072); // 128 KiB
  float* scores = (float*)(ws + (32ull << 20) + 262144); // 16 MiB
  float* ctx    = (float*)(ws + (48ull << 20) + 262144); // 64 MiB -> 112.25 MiB
  float* ln2out = scores;                                // reuse
  float* hbuf   = nq;                                    // reuse nq+qkv (32 MiB)

  // 1. LN1 (frozen)
  ln_np<<<dim3(NB * SQ), 64, 0, stream>>>(query, ln1_g, ln1_b, nq);
  // 2. distances (frozen)
  dist_np<<<dim3(NB * NH), 256, 0, stream>>>(nq, conv_w, conv_b, dist);
  // 3. qkv (sgemm KC=384, bit-identical chain)  M=4096 N=1536 K=512
  gemm_nt<0, 384><<<dim3(24, 64, 1), 256, 0, stream>>>(nq, EE, 0, in_proj_w, EE, 0,
                                                       in_proj_b, nullptr, qkv, 3 * EE, 0, EE, 1.f);
  // 4. scores (frozen chain + true division)  M=N=1024 K=512, batched B
  gemm_nt<2, 384><<<dim3(16, 16, NB), 256, 0, stream>>>(
      qkv, 3 * EE, (long long)SQ * 3 * EE, qkv + EE, 3 * EE, (long long)SQ * 3 * EE,
      nullptr, nullptr, scores, SQ, (long long)SQ * SQ, EE, sqrtf(512.0f));
  // 5. gated row sums (frozen)
  rowsum_np<<<dim3(SQ, NB * NH), 64, 0, stream>>>(scores, dist, invrs);
  // 6. ctx wide-N nc=4 (batched over b,h)  M=1024 N=512 K=1024
  ctx_gemm_w<<<dim3(2, 16, NB * NH), 256, 0, stream>>>(scores, dist, invrs, qkv, ctx);
  // 7. attn_out + residual  M=4096 N=512 K=4096
  gemm_nt<0, 0><<<dim3(8, 64, 1), 256, 0, stream>>>(ctx, NH * EE, 0, out_w, NH * EE, 0,
                                                    out_b, query, out, EE, 0, NH * EE, 1.f);
  // 8. LN2
  ln_np<<<dim3(NB * SQ), 64, 0, stream>>>(out, ln2_g, ln2_b, ln2out);
  // 9. MLP1 + gelu  M=4096 N=2048 K=512
  gemm_nt<1, 0><<<dim3(32, 64, 1), 256, 0, stream>>>(ln2out, EE, 0, mlp_w1, EE, 0,
                                                     mlp_b1, nullptr, hbuf, 4 * EE, 0, EE, 1.f);
  // 10. MLP2 + residual  M=4096 N=512 K=2048
  gemm_nt<0, 0><<<dim3(8, 64, 1), 256, 0, stream>>>(hbuf, 4 * EE, 0, mlp_w2, 4 * EE, 0,
                                                    mlp_b2, out, out, EE, 0, 4 * EE, 1.f);
}

// Round 12
// 1466.977 us; speedup vs baseline: 1.2955x; 1.0377x over previous
//
#include <hip/hip_runtime.h>
#include <math.h>

#define SQ 1024  // S
#define EE 512   // E
#define NB 4     // B
#define NH 8     // H

// Optimization barrier: forces materialization (rounding) so the compiler
// cannot FMA-contract or reassociate across numpy's op boundaries.
__device__ __forceinline__ float sep(float x) {
  asm volatile("" : "+v"(x));
  return x;
}

// ================= LayerNorm, numpy-exact fp32 (np.mean pairwise) — FROZEN =================
__global__ __launch_bounds__(64) void ln_np(const float* __restrict__ x,
                                            const float* __restrict__ g,
                                            const float* __restrict__ b,
                                            float* __restrict__ y) {
  __shared__ float xs[EE];
  __shared__ float bc[2];
  long long t = blockIdx.x;
  int lane = threadIdx.x;
#pragma unroll
  for (int m = 0; m < 8; m++) xs[lane + 64 * m] = x[t * EE + lane + 64 * m];
  __syncthreads();
  int l = lane >> 3, a = lane & 7;
  float r = 0.f;
  if (lane < 32) {
    r = xs[l * 128 + a];
#pragma unroll
    for (int m = 1; m < 16; m++) r = r + xs[l * 128 + 8 * m + a];
  }
  r = r + __shfl_xor(r, 1);
  r = r + __shfl_xor(r, 2);
  r = r + __shfl_xor(r, 4);
  r = r + __shfl_xor(r, 8);
  r = r + __shfl_xor(r, 16);
  if (lane == 0) bc[0] = r / 512.0f;
  __syncthreads();
  float mean = bc[0];
  r = 0.f;
  if (lane < 32) {
#pragma unroll
    for (int m = 0; m < 16; m++) {
      float d = sep(xs[l * 128 + 8 * m + a] - mean);
      float s2 = sep(d * d);
      r = (m == 0) ? s2 : (r + s2);
    }
  }
  r = r + __shfl_xor(r, 1);
  r = r + __shfl_xor(r, 2);
  r = r + __shfl_xor(r, 4);
  r = r + __shfl_xor(r, 8);
  r = r + __shfl_xor(r, 16);
  if (lane == 0) bc[1] = r / 512.0f;
  __syncthreads();
  float var = bc[1];
  float rs = 1.0f / sqrtf(var + 1e-5f);
#pragma unroll
  for (int m = 0; m < 8; m++) {
    int i = lane + 64 * m;
    float d = sep(xs[i] - mean);
    float t1 = sep(d * rs);
    float t2 = sep(t1 * g[i]);
    y[t * EE + i] = t2 + b[i];
  }
}

// ================= distances — FROZEN math; s-range split over blockIdx.y =================
__global__ __launch_bounds__(256) void dist_np(const float* __restrict__ nq,
                                               const float* __restrict__ conv_w,
                                               const float* __restrict__ conv_b,
                                               float* __restrict__ dist) {
  int bh = blockIdx.x;
  int b = bh >> 3, h = bh & 7;
  float cb = conv_b[h];
  const float* W = conv_w + (long long)h * EE * 3;
  int s = blockIdx.y * 256 + threadIdx.x;
  float d = cb;
#pragma unroll
  for (int k = 0; k < 3; k++) {
    int t = s - 2 + k;
    if (t < 0) continue;
    const float* row = nq + ((long long)b * SQ + t) * EE;
    float acc = 0.f;
    for (int e = 0; e < EE; e++) acc = __builtin_fmaf(row[e], W[e * 3 + k], acc);
    d = sep(d + acc);
  }
  dist[(long long)bh * SQ + s] = (float)tanh((double)d);
}

// ================= fp32 tiled NT-GEMM — R7 arithmetic DAG, register-prefetch pipeline =================
// Per-output-element numerics IDENTICAL to R7: ascending-k FMA chain, SPLITK
// merge, sep() epilogue. Only the load SCHEDULE changed: tile k+1 is fetched
// into registers while tile k's FMAs issue, so vmcnt waits overlap compute.
__device__ __forceinline__ float gelu_exact(float x) {
  return 0.5f * x * (1.f + erff(x / 1.41421356237309504880f));
}

template <int ACT, int SPLITK>
__global__ __launch_bounds__(256) void gemm_nt(const float* __restrict__ A, int lda, long long sA,
                                               const float* __restrict__ B, int ldb, long long sB,
                                               const float* __restrict__ bias,
                                               const float* __restrict__ Res,
                                               float* __restrict__ C, int ldc, long long sC,
                                               int K, float alpha) {
  __shared__ float As[16][68];
  __shared__ float Bs[16][68];
  int z = blockIdx.z;
  A += (long long)z * sA;
  B += (long long)z * sB;
  C += (long long)z * sC;
  int m0 = blockIdx.y * 64, n0 = blockIdx.x * 64;
  int tid = threadIdx.x;
  int lr = tid >> 2, lc = tid & 3;
  int tx = tid & 15, ty = tid >> 4;
  float acc[4][4] = {};
  float acc2[4][4] = {};
  const float* Arow = A + (long long)(m0 + lr) * lda + lc * 4;
  const float* Brow = B + (long long)(n0 + lr) * ldb + lc * 4;
  float4 a4 = *(const float4*)(Arow);
  float4 b4 = *(const float4*)(Brow);
  for (int k0 = 0; k0 < K; k0 += 16) {
    __syncthreads();
    As[lc * 4 + 0][lr] = a4.x; As[lc * 4 + 1][lr] = a4.y;
    As[lc * 4 + 2][lr] = a4.z; As[lc * 4 + 3][lr] = a4.w;
    Bs[lc * 4 + 0][lr] = b4.x; Bs[lc * 4 + 1][lr] = b4.y;
    Bs[lc * 4 + 2][lr] = b4.z; Bs[lc * 4 + 3][lr] = b4.w;
    __syncthreads();
    int kn = (k0 + 16 < K) ? (k0 + 16) : k0;  // clamped dummy reload on last iter
    float4 a4n = *(const float4*)(Arow + kn);
    float4 b4n = *(const float4*)(Brow + kn);
    float(*tgt)[4] = (SPLITK > 0 && k0 >= SPLITK) ? acc2 : acc;
#pragma unroll
    for (int kk = 0; kk < 16; kk++) {
      float4 av = *(const float4*)&As[kk][ty * 4];
      float4 bv = *(const float4*)&Bs[kk][tx * 4];
      float a[4] = {av.x, av.y, av.z, av.w};
      float bb[4] = {bv.x, bv.y, bv.z, bv.w};
#pragma unroll
      for (int i = 0; i < 4; i++)
#pragma unroll
        for (int j = 0; j < 4; j++) tgt[i][j] += a[i] * bb[j];
    }
    a4 = a4n;
    b4 = b4n;
  }
  if (SPLITK > 0) {
#pragma unroll
    for (int i = 0; i < 4; i++)
#pragma unroll
      for (int j = 0; j < 4; j++) acc[i][j] = sep(acc[i][j]) + acc2[i][j];
  }
  float4 bias4 = make_float4(0.f, 0.f, 0.f, 0.f);
  if (ACT != 2 && bias) bias4 = *(const float4*)(bias + n0 + tx * 4);
#pragma unroll
  for (int i = 0; i < 4; i++) {
    int row = m0 + ty * 4 + i;
    float o[4];
    if (ACT == 2) {
#pragma unroll
      for (int j = 0; j < 4; j++) o[j] = acc[i][j] / alpha;
    } else {
      o[0] = sep(acc[i][0] * alpha) + bias4.x;
      o[1] = sep(acc[i][1] * alpha) + bias4.y;
      o[2] = sep(acc[i][2] * alpha) + bias4.z;
      o[3] = sep(acc[i][3] * alpha) + bias4.w;
    }
    if (ACT == 1) {
#pragma unroll
      for (int j = 0; j < 4; j++) o[j] = gelu_exact(o[j]);
    }
    if (Res) {
      float4 r4 = *(const float4*)(Res + (long long)row * ldc + n0 + tx * 4);
      o[0] = sep(o[0]) + r4.x; o[1] = sep(o[1]) + r4.y;
      o[2] = sep(o[2]) + r4.z; o[3] = sep(o[3]) + r4.w;
    }
    *(float4*)(C + (long long)row * ldc + n0 + tx * 4) = make_float4(o[0], o[1], o[2], o[3]);
  }
}

// ================= gated row sums: np.sum pairwise(1024) — FROZEN =================
__global__ __launch_bounds__(64) void rowsum_np(const float* __restrict__ scores,
                                                const float* __restrict__ dist,
                                                float* __restrict__ invrs) {
  __shared__ float wsm[SQ];
  int i = blockIdx.x;
  int z = blockIdx.y;
  int b = z >> 3;
  const float* srow = scores + ((long long)b * SQ + i) * SQ;
  const float* dz = dist + (long long)z * SQ;
  float di = dz[i];
  int lane = threadIdx.x;
#pragma unroll
  for (int m = 0; m < 16; m++) {
    int j = lane + 64 * m;
    float e = (float)exp((double)(dz[j] - di));
    float gg = 1.f / (1.f + e);
    wsm[j] = srow[j] * gg;
  }
  __syncthreads();
  int l = lane >> 3, a = lane & 7;
  float r = wsm[l * 128 + a];
#pragma unroll
  for (int m = 1; m < 16; m++) r = r + wsm[l * 128 + 8 * m + a];
  r = r + __shfl_xor(r, 1);
  r = r + __shfl_xor(r, 2);
  r = r + __shfl_xor(r, 4);
  r = r + __shfl_xor(r, 8);
  r = r + __shfl_xor(r, 16);
  r = r + __shfl_xor(r, 32);
  if (lane == 0) invrs[(long long)z * SQ + i] = 1.f / (r + 1e-12f);
}

// ================= ctx GEMM wide-N (nc=4) — R11 DAG, register-prefetch pipeline =================
// Same staging expressions and per-element k-ascending FMA chains as R11;
// only the load schedule changed (prefetch s/dist/V for k+1 during compute).
__global__ __launch_bounds__(256) void ctx_gemm_w(const float* __restrict__ scores,
                                                  const float* __restrict__ dist,
                                                  const float* __restrict__ invrs,
                                                  const float* __restrict__ qkv,
                                                  float* __restrict__ ctx) {
  __shared__ float As[16][68];
  __shared__ float Bs[16][264];  // 256 cols + 8 pad
  int z = blockIdx.z, b = z >> 3, h = z & 7;
  const float* A = scores + (long long)b * SQ * SQ;
  const float* V = qkv + (long long)b * SQ * (3 * EE) + 2 * EE;
  float* C = ctx + (long long)b * SQ * (NH * EE) + h * EE;
  const float* dz = dist + (long long)z * SQ;
  int m0 = blockIdx.y * 64;
  int n0 = blockIdx.x * 256;
  int tid = threadIdx.x;
  int lr = tid >> 2, lc = tid & 3;
  int bk = tid >> 4, bc = tid & 15;
  int tx = tid & 15, ty = tid >> 4;
  int arow = m0 + lr;
  float di = dz[arow];
  float inv = invrs[(long long)z * SQ + arow];
  float acc[4][4][4] = {};
  const float* Srow = A + (long long)arow * SQ + lc * 4;
  const float* Vbase = V + (long long)bk * (3 * EE) + n0 + bc * 4;
  float4 s4 = *(const float4*)(Srow);
  float4 d4 = *(const float4*)(dz + lc * 4);
  float4 v4[4];
#pragma unroll
  for (int nc = 0; nc < 4; nc++) v4[nc] = *(const float4*)(Vbase + nc * 64);
  for (int k0 = 0; k0 < SQ; k0 += 16) {
    __syncthreads();
    float g0 = 1.f / (1.f + expf(d4.x - di));
    float g1 = 1.f / (1.f + expf(d4.y - di));
    float g2 = 1.f / (1.f + expf(d4.z - di));
    float g3 = 1.f / (1.f + expf(d4.w - di));
    As[lc * 4 + 0][lr] = (s4.x * g0) * inv;
    As[lc * 4 + 1][lr] = (s4.y * g1) * inv;
    As[lc * 4 + 2][lr] = (s4.z * g2) * inv;
    As[lc * 4 + 3][lr] = (s4.w * g3) * inv;
#pragma unroll
    for (int nc = 0; nc < 4; nc++)
      *(float4*)&Bs[bk][nc * 64 + bc * 4] = v4[nc];
    __syncthreads();
    int kn = (k0 + 16 < SQ) ? (k0 + 16) : k0;  // clamped dummy reload on last iter
    float4 s4n = *(const float4*)(Srow + kn);
    float4 d4n = *(const float4*)(dz + kn + lc * 4);
    float4 v4n[4];
#pragma unroll
    for (int nc = 0; nc < 4; nc++)
      v4n[nc] = *(const float4*)(Vbase + (long long)kn * (3 * EE) + nc * 64);
#pragma unroll
    for (int kk = 0; kk < 16; kk++) {
      float4 av = *(const float4*)&As[kk][ty * 4];
      float a[4] = {av.x, av.y, av.z, av.w};
#pragma unroll
      for (int nc = 0; nc < 4; nc++) {
        float4 bv = *(const float4*)&Bs[kk][nc * 64 + tx * 4];
        float bb[4] = {bv.x, bv.y, bv.z, bv.w};
#pragma unroll
        for (int i = 0; i < 4; i++)
#pragma unroll
          for (int j = 0; j < 4; j++) acc[nc][i][j] += a[i] * bb[j];
      }
    }
    s4 = s4n;
    d4 = d4n;
#pragma unroll
    for (int nc = 0; nc < 4; nc++) v4[nc] = v4n[nc];
  }
#pragma unroll
  for (int i = 0; i < 4; i++) {
    int row = m0 + ty * 4 + i;
#pragma unroll
    for (int nc = 0; nc < 4; nc++) {
      *(float4*)(C + (long long)row * (NH * EE) + n0 + nc * 64 + tx * 4) =
          make_float4(acc[nc][i][0], acc[nc][i][1], acc[nc][i][2], acc[nc][i][3]);
    }
  }
}

extern "C" void kernel_launch(void* const* d_in, const int* in_sizes, int n_in,
                              void* d_out, int out_size, void* d_ws, size_t ws_size,
                              hipStream_t stream) {
  const float* query     = (const float*)d_in[0];
  const float* ln1_g     = (const float*)d_in[1];
  const float* ln1_b     = (const float*)d_in[2];
  const float* in_proj_w = (const float*)d_in[3];
  const float* in_proj_b = (const float*)d_in[4];
  const float* out_w     = (const float*)d_in[5];
  const float* out_b     = (const float*)d_in[6];
  const float* conv_w    = (const float*)d_in[7];
  const float* conv_b    = (const float*)d_in[8];
  const float* ln2_g     = (const float*)d_in[9];
  const float* ln2_b     = (const float*)d_in[10];
  const float* mlp_w1    = (const float*)d_in[11];
  const float* mlp_b1    = (const float*)d_in[12];
  const float* mlp_w2    = (const float*)d_in[13];
  const float* mlp_b2    = (const float*)d_in[14];
  float* out = (float*)d_out;
  char* ws = (char*)d_ws;

  // R7-exact layout: peak 112.25 MiB (proven safe in R1/R7/R10/R11)
  float* nq     = (float*)(ws + 0);                      // 8 MiB
  float* qkv    = (float*)(ws + (8ull << 20));           // 24 MiB
  float* dist   = (float*)(ws + (32ull << 20));          // 128 KiB
  float* invrs  = (float*)(ws + (32ull << 20) + 131072); // 128 KiB
  float* scores = (float*)(ws + (32ull << 20) + 262144); // 16 MiB
  float* ctx    = (float*)(ws + (48ull << 20) + 262144); // 64 MiB -> 112.25 MiB
  float* ln2out = scores;                                // reuse
  float* hbuf   = nq;                                    // reuse nq+qkv (32 MiB)

  // 1. LN1 (frozen)
  ln_np<<<dim3(NB * SQ), 64, 0, stream>>>(query, ln1_g, ln1_b, nq);
  // 2. distances (frozen math; 4x more blocks)
  dist_np<<<dim3(NB * NH, 4), 256, 0, stream>>>(nq, conv_w, conv_b, dist);
  // 3. qkv (sgemm KC=384, bit-identical chain)  M=4096 N=1536 K=512
  gemm_nt<0, 384><<<dim3(24, 64, 1), 256, 0, stream>>>(nq, EE, 0, in_proj_w, EE, 0,
                                                       in_proj_b, nullptr, qkv, 3 * EE, 0, EE, 1.f);
  // 4. scores (frozen chain + true division)  M=N=1024 K=512, batched B
  gemm_nt<2, 384><<<dim3(16, 16, NB), 256, 0, stream>>>(
      qkv, 3 * EE, (long long)SQ * 3 * EE, qkv + EE, 3 * EE, (long long)SQ * 3 * EE,
      nullptr, nullptr, scores, SQ, (long long)SQ * SQ, EE, sqrtf(512.0f));
  // 5. gated row sums (frozen)
  rowsum_np<<<dim3(SQ, NB * NH), 64, 0, stream>>>(scores, dist, invrs);
  // 6. ctx wide-N nc=4 (batched over b,h)  M=1024 N=512 K=1024
  ctx_gemm_w<<<dim3(2, 16, NB * NH), 256, 0, stream>>>(scores, dist, invrs, qkv, ctx);
  // 7. attn_out + residual  M=4096 N=512 K=4096
  gemm_nt<0, 0><<<dim3(8, 64, 1), 256, 0, stream>>>(ctx, NH * EE, 0, out_w, NH * EE, 0,
                                                    out_b, query, out, EE, 0, NH * EE, 1.f);
  // 8. LN2
  ln_np<<<dim3(NB * SQ), 64, 0, stream>>>(out, ln2_g, ln2_b, ln2out);
  // 9. MLP1 + gelu  M=4096 N=2048 K=512
  gemm_nt<1, 0><<<dim3(32, 64, 1), 256, 0, stream>>>(ln2out, EE, 0, mlp_w1, EE, 0,
                                                     mlp_b1, nullptr, hbuf, 4 * EE, 0, EE, 1.f);
  // 10. MLP2 + residual  M=4096 N=512 K=2048
  gemm_nt<0, 0><<<dim3(8, 64, 1), 256, 0, stream>>>(hbuf, 4 * EE, 0, mlp_w2, 4 * EE, 0,
                                                    mlp_b2, out, out, EE, 0, 4 * EE, 1.f);
}

// Round 13
// 1317.561 us; speedup vs baseline: 1.4425x; 1.1134x over previous
//
#include <hip/hip_runtime.h>
#include <math.h>

#define SQ 1024  // S
#define EE 512   // E
#define NB 4     // B
#define NH 8     // H

typedef __attribute__((ext_vector_type(8))) short bfrag;       // 8 bf16 (4 VGPRs)
typedef __attribute__((ext_vector_type(4))) float f32x4;       // MFMA C/D
typedef __attribute__((ext_vector_type(4))) unsigned short u16x4;

// Optimization barrier: forces materialization (rounding) so the compiler
// cannot FMA-contract or reassociate across numpy's op boundaries.
__device__ __forceinline__ float sep(float x) {
  asm volatile("" : "+v"(x));
  return x;
}

__device__ __forceinline__ unsigned short f2bf(float f) {
  unsigned u = __builtin_bit_cast(unsigned, f);
  unsigned r = (u + 0x7fffu + ((u >> 16) & 1u)) >> 16;
  return (unsigned short)r;
}
__device__ __forceinline__ float bf2f(unsigned short h) {
  unsigned u = ((unsigned)h) << 16;
  return __builtin_bit_cast(float, u);
}

// ================= LayerNorm, numpy-exact fp32 (np.mean pairwise) — FROZEN =================
__global__ __launch_bounds__(64) void ln_np(const float* __restrict__ x,
                                            const float* __restrict__ g,
                                            const float* __restrict__ b,
                                            float* __restrict__ y) {
  __shared__ float xs[EE];
  __shared__ float bc[2];
  long long t = blockIdx.x;
  int lane = threadIdx.x;
#pragma unroll
  for (int m = 0; m < 8; m++) xs[lane + 64 * m] = x[t * EE + lane + 64 * m];
  __syncthreads();
  int l = lane >> 3, a = lane & 7;
  float r = 0.f;
  if (lane < 32) {
    r = xs[l * 128 + a];
#pragma unroll
    for (int m = 1; m < 16; m++) r = r + xs[l * 128 + 8 * m + a];
  }
  r = r + __shfl_xor(r, 1);
  r = r + __shfl_xor(r, 2);
  r = r + __shfl_xor(r, 4);
  r = r + __shfl_xor(r, 8);
  r = r + __shfl_xor(r, 16);
  if (lane == 0) bc[0] = r / 512.0f;
  __syncthreads();
  float mean = bc[0];
  r = 0.f;
  if (lane < 32) {
#pragma unroll
    for (int m = 0; m < 16; m++) {
      float d = sep(xs[l * 128 + 8 * m + a] - mean);
      float s2 = sep(d * d);
      r = (m == 0) ? s2 : (r + s2);
    }
  }
  r = r + __shfl_xor(r, 1);
  r = r + __shfl_xor(r, 2);
  r = r + __shfl_xor(r, 4);
  r = r + __shfl_xor(r, 8);
  r = r + __shfl_xor(r, 16);
  if (lane == 0) bc[1] = r / 512.0f;
  __syncthreads();
  float var = bc[1];
  float rs = 1.0f / sqrtf(var + 1e-5f);
#pragma unroll
  for (int m = 0; m < 8; m++) {
    int i = lane + 64 * m;
    float d = sep(xs[i] - mean);
    float t1 = sep(d * rs);
    float t2 = sep(t1 * g[i]);
    y[t * EE + i] = t2 + b[i];
  }
}

// ================= distances — FROZEN math; s-range split over blockIdx.y =================
__global__ __launch_bounds__(256) void dist_np(const float* __restrict__ nq,
                                               const float* __restrict__ conv_w,
                                               const float* __restrict__ conv_b,
                                               float* __restrict__ dist) {
  int bh = blockIdx.x;
  int b = bh >> 3, h = bh & 7;
  float cb = conv_b[h];
  const float* W = conv_w + (long long)h * EE * 3;
  int s = blockIdx.y * 256 + threadIdx.x;
  float d = cb;
#pragma unroll
  for (int k = 0; k < 3; k++) {
    int t = s - 2 + k;
    if (t < 0) continue;
    const float* row = nq + ((long long)b * SQ + t) * EE;
    float acc = 0.f;
    for (int e = 0; e < EE; e++) acc = __builtin_fmaf(row[e], W[e * 3 + k], acc);
    d = sep(d + acc);
  }
  dist[(long long)bh * SQ + s] = (float)tanh((double)d);
}

// ================= fp32 tiled NT-GEMM — FROZEN DAG (R12, byte-identical) =================
__device__ __forceinline__ float gelu_exact(float x) {
  return 0.5f * x * (1.f + erff(x / 1.41421356237309504880f));
}

template <int ACT, int SPLITK>
__global__ __launch_bounds__(256) void gemm_nt(const float* __restrict__ A, int lda, long long sA,
                                               const float* __restrict__ B, int ldb, long long sB,
                                               const float* __restrict__ bias,
                                               const float* __restrict__ Res,
                                               float* __restrict__ C, int ldc, long long sC,
                                               int K, float alpha) {
  __shared__ float As[16][68];
  __shared__ float Bs[16][68];
  int z = blockIdx.z;
  A += (long long)z * sA;
  B += (long long)z * sB;
  C += (long long)z * sC;
  int m0 = blockIdx.y * 64, n0 = blockIdx.x * 64;
  int tid = threadIdx.x;
  int lr = tid >> 2, lc = tid & 3;
  int tx = tid & 15, ty = tid >> 4;
  float acc[4][4] = {};
  float acc2[4][4] = {};
  const float* Arow = A + (long long)(m0 + lr) * lda + lc * 4;
  const float* Brow = B + (long long)(n0 + lr) * ldb + lc * 4;
  float4 a4 = *(const float4*)(Arow);
  float4 b4 = *(const float4*)(Brow);
  for (int k0 = 0; k0 < K; k0 += 16) {
    __syncthreads();
    As[lc * 4 + 0][lr] = a4.x; As[lc * 4 + 1][lr] = a4.y;
    As[lc * 4 + 2][lr] = a4.z; As[lc * 4 + 3][lr] = a4.w;
    Bs[lc * 4 + 0][lr] = b4.x; Bs[lc * 4 + 1][lr] = b4.y;
    Bs[lc * 4 + 2][lr] = b4.z; Bs[lc * 4 + 3][lr] = b4.w;
    __syncthreads();
    int kn = (k0 + 16 < K) ? (k0 + 16) : k0;
    float4 a4n = *(const float4*)(Arow + kn);
    float4 b4n = *(const float4*)(Brow + kn);
    float(*tgt)[4] = (SPLITK > 0 && k0 >= SPLITK) ? acc2 : acc;
#pragma unroll
    for (int kk = 0; kk < 16; kk++) {
      float4 av = *(const float4*)&As[kk][ty * 4];
      float4 bv = *(const float4*)&Bs[kk][tx * 4];
      float a[4] = {av.x, av.y, av.z, av.w};
      float bb[4] = {bv.x, bv.y, bv.z, bv.w};
#pragma unroll
      for (int i = 0; i < 4; i++)
#pragma unroll
        for (int j = 0; j < 4; j++) tgt[i][j] += a[i] * bb[j];
    }
    a4 = a4n;
    b4 = b4n;
  }
  if (SPLITK > 0) {
#pragma unroll
    for (int i = 0; i < 4; i++)
#pragma unroll
      for (int j = 0; j < 4; j++) acc[i][j] = sep(acc[i][j]) + acc2[i][j];
  }
  float4 bias4 = make_float4(0.f, 0.f, 0.f, 0.f);
  if (ACT != 2 && bias) bias4 = *(const float4*)(bias + n0 + tx * 4);
#pragma unroll
  for (int i = 0; i < 4; i++) {
    int row = m0 + ty * 4 + i;
    float o[4];
    if (ACT == 2) {
#pragma unroll
      for (int j = 0; j < 4; j++) o[j] = acc[i][j] / alpha;
    } else {
      o[0] = sep(acc[i][0] * alpha) + bias4.x;
      o[1] = sep(acc[i][1] * alpha) + bias4.y;
      o[2] = sep(acc[i][2] * alpha) + bias4.z;
      o[3] = sep(acc[i][3] * alpha) + bias4.w;
    }
    if (ACT == 1) {
#pragma unroll
      for (int j = 0; j < 4; j++) o[j] = gelu_exact(o[j]);
    }
    if (Res) {
      float4 r4 = *(const float4*)(Res + (long long)row * ldc + n0 + tx * 4);
      o[0] = sep(o[0]) + r4.x; o[1] = sep(o[1]) + r4.y;
      o[2] = sep(o[2]) + r4.z; o[3] = sep(o[3]) + r4.w;
    }
    *(float4*)(C + (long long)row * ldc + n0 + tx * 4) = make_float4(o[0], o[1], o[2], o[3]);
  }
}

// ================= gated row sums: np.sum pairwise(1024) — FROZEN =================
__global__ __launch_bounds__(64) void rowsum_np(const float* __restrict__ scores,
                                                const float* __restrict__ dist,
                                                float* __restrict__ invrs) {
  __shared__ float wsm[SQ];
  int i = blockIdx.x;
  int z = blockIdx.y;
  int b = z >> 3;
  const float* srow = scores + ((long long)b * SQ + i) * SQ;
  const float* dz = dist + (long long)z * SQ;
  float di = dz[i];
  int lane = threadIdx.x;
#pragma unroll
  for (int m = 0; m < 16; m++) {
    int j = lane + 64 * m;
    float e = (float)exp((double)(dz[j] - di));
    float gg = 1.f / (1.f + e);
    wsm[j] = srow[j] * gg;
  }
  __syncthreads();
  int l = lane >> 3, a = lane & 7;
  float r = wsm[l * 128 + a];
#pragma unroll
  for (int m = 1; m < 16; m++) r = r + wsm[l * 128 + 8 * m + a];
  r = r + __shfl_xor(r, 1);
  r = r + __shfl_xor(r, 2);
  r = r + __shfl_xor(r, 4);
  r = r + __shfl_xor(r, 8);
  r = r + __shfl_xor(r, 16);
  r = r + __shfl_xor(r, 32);
  if (lane == 0) invrs[(long long)z * SQ + i] = 1.f / (r + 1e-12f);
}

// ================= ctx GEMM wide-N (nc=4) — PROVEN (R12, byte-identical) =================
__global__ __launch_bounds__(256) void ctx_gemm_w(const float* __restrict__ scores,
                                                  const float* __restrict__ dist,
                                                  const float* __restrict__ invrs,
                                                  const float* __restrict__ qkv,
                                                  float* __restrict__ ctx) {
  __shared__ float As[16][68];
  __shared__ float Bs[16][264];
  int z = blockIdx.z, b = z >> 3, h = z & 7;
  const float* A = scores + (long long)b * SQ * SQ;
  const float* V = qkv + (long long)b * SQ * (3 * EE) + 2 * EE;
  float* C = ctx + (long long)b * SQ * (NH * EE) + h * EE;
  const float* dz = dist + (long long)z * SQ;
  int m0 = blockIdx.y * 64;
  int n0 = blockIdx.x * 256;
  int tid = threadIdx.x;
  int lr = tid >> 2, lc = tid & 3;
  int bk = tid >> 4, bc = tid & 15;
  int tx = tid & 15, ty = tid >> 4;
  int arow = m0 + lr;
  float di = dz[arow];
  float inv = invrs[(long long)z * SQ + arow];
  float acc[4][4][4] = {};
  const float* Srow = A + (long long)arow * SQ + lc * 4;
  const float* Vbase = V + (long long)bk * (3 * EE) + n0 + bc * 4;
  float4 s4 = *(const float4*)(Srow);
  float4 d4 = *(const float4*)(dz + lc * 4);
  float4 v4[4];
#pragma unroll
  for (int nc = 0; nc < 4; nc++) v4[nc] = *(const float4*)(Vbase + nc * 64);
  for (int k0 = 0; k0 < SQ; k0 += 16) {
    __syncthreads();
    float g0 = 1.f / (1.f + expf(d4.x - di));
    float g1 = 1.f / (1.f + expf(d4.y - di));
    float g2 = 1.f / (1.f + expf(d4.z - di));
    float g3 = 1.f / (1.f + expf(d4.w - di));
    As[lc * 4 + 0][lr] = (s4.x * g0) * inv;
    As[lc * 4 + 1][lr] = (s4.y * g1) * inv;
    As[lc * 4 + 2][lr] = (s4.z * g2) * inv;
    As[lc * 4 + 3][lr] = (s4.w * g3) * inv;
#pragma unroll
    for (int nc = 0; nc < 4; nc++)
      *(float4*)&Bs[bk][nc * 64 + bc * 4] = v4[nc];
    __syncthreads();
    int kn = (k0 + 16 < SQ) ? (k0 + 16) : k0;
    float4 s4n = *(const float4*)(Srow + kn);
    float4 d4n = *(const float4*)(dz + kn + lc * 4);
    float4 v4n[4];
#pragma unroll
    for (int nc = 0; nc < 4; nc++)
      v4n[nc] = *(const float4*)(Vbase + (long long)kn * (3 * EE) + nc * 64);
#pragma unroll
    for (int kk = 0; kk < 16; kk++) {
      float4 av = *(const float4*)&As[kk][ty * 4];
      float a[4] = {av.x, av.y, av.z, av.w};
#pragma unroll
      for (int nc = 0; nc < 4; nc++) {
        float4 bv = *(const float4*)&Bs[kk][nc * 64 + tx * 4];
        float bb[4] = {bv.x, bv.y, bv.z, bv.w};
#pragma unroll
        for (int i = 0; i < 4; i++)
#pragma unroll
          for (int j = 0; j < 4; j++) acc[nc][i][j] += a[i] * bb[j];
      }
    }
    s4 = s4n;
    d4 = d4n;
#pragma unroll
    for (int nc = 0; nc < 4; nc++) v4[nc] = v4n[nc];
  }
#pragma unroll
  for (int i = 0; i < 4; i++) {
    int row = m0 + ty * 4 + i;
#pragma unroll
    for (int nc = 0; nc < 4; nc++) {
      *(float4*)(C + (long long)row * (NH * EE) + n0 + nc * 64 + tx * 4) =
          make_float4(acc[nc][i][0], acc[nc][i][1], acc[nc][i][2], acc[nc][i][3]);
    }
  }
}

// ================= bf16x3 MFMA NT-GEMM (numerator-side only) =================
// C = act(A@B^T + bias) (+Res). fp32 split into hi/lo bf16; 3 MFMA terms per
// product (rel err ~2^-17). Tile 64 x BN, 4 waves, K-step 32, mfma 16x16x32.
template <int ACT, int BN>
__global__ __launch_bounds__(256) void gemm_bf3(const float* __restrict__ A, int lda,
                                                const float* __restrict__ B, int ldb,
                                                const float* __restrict__ bias,
                                                const float* __restrict__ Res,
                                                float* __restrict__ C, int ldc, int K) {
  constexpr int NF = BN / 64;        // n-frags per wave (16 cols each)
  constexpr int NREPB = BN / 32;     // B staging reps (float4 per thread)
  __shared__ __align__(16) unsigned short Ah[64][40], Al[64][40];
  __shared__ __align__(16) unsigned short Bh[BN][40], Bl[BN][40];
  int m0 = blockIdx.y * 64, n0 = blockIdx.x * BN;
  int tid = threadIdx.x;
  int wave = tid >> 6, lane = tid & 63;
  int quad = lane >> 4, l16 = lane & 15;
  int colb0 = wave * (BN / 4);
  f32x4 acc[4][NF];
#pragma unroll
  for (int mf = 0; mf < 4; mf++)
#pragma unroll
    for (int nf = 0; nf < NF; nf++) acc[mf][nf] = (f32x4)(0.f);

  int aam = tid & 63, aakc = tid >> 6;            // +r*4 on kc per rep
  float4 aldg[2], bldg[NREPB];
#pragma unroll
  for (int r = 0; r < 2; r++)
    aldg[r] = *(const float4*)(A + (long long)(m0 + aam) * lda + (aakc + r * 4) * 4);
  int bbn = tid & (BN - 1), bbkc = tid / BN;
#pragma unroll
  for (int r = 0; r < NREPB; r++)
    bldg[r] = *(const float4*)(B + (long long)(n0 + bbn) * ldb + (bbkc + r * (256 / BN)) * 4);

  for (int k0 = 0; k0 < K; k0 += 32) {
    __syncthreads();
#pragma unroll
    for (int r = 0; r < 2; r++) {
      float4 v = aldg[r];
      int kc = aakc + r * 4;
      u16x4 h, l;
      h.x = f2bf(v.x); l.x = f2bf(v.x - bf2f(h.x));
      h.y = f2bf(v.y); l.y = f2bf(v.y - bf2f(h.y));
      h.z = f2bf(v.z); l.z = f2bf(v.z - bf2f(h.z));
      h.w = f2bf(v.w); l.w = f2bf(v.w - bf2f(h.w));
      *(u16x4*)&Ah[aam][kc * 4] = h;
      *(u16x4*)&Al[aam][kc * 4] = l;
    }
#pragma unroll
    for (int r = 0; r < NREPB; r++) {
      float4 v = bldg[r];
      int kc = bbkc + r * (256 / BN);
      u16x4 h, l;
      h.x = f2bf(v.x); l.x = f2bf(v.x - bf2f(h.x));
      h.y = f2bf(v.y); l.y = f2bf(v.y - bf2f(h.y));
      h.z = f2bf(v.z); l.z = f2bf(v.z - bf2f(h.z));
      h.w = f2bf(v.w); l.w = f2bf(v.w - bf2f(h.w));
      *(u16x4*)&Bh[bbn][kc * 4] = h;
      *(u16x4*)&Bl[bbn][kc * 4] = l;
    }
    __syncthreads();
    int kn = (k0 + 32 < K) ? (k0 + 32) : k0;  // clamped dummy reload
#pragma unroll
    for (int r = 0; r < 2; r++)
      aldg[r] = *(const float4*)(A + (long long)(m0 + aam) * lda + kn + (aakc + r * 4) * 4);
#pragma unroll
    for (int r = 0; r < NREPB; r++)
      bldg[r] = *(const float4*)(B + (long long)(n0 + bbn) * ldb + kn + (bbkc + r * (256 / BN)) * 4);
    bfrag bh[NF], bl[NF];
#pragma unroll
    for (int nf = 0; nf < NF; nf++) {
      bh[nf] = *(const bfrag*)&Bh[colb0 + nf * 16 + l16][quad * 8];
      bl[nf] = *(const bfrag*)&Bl[colb0 + nf * 16 + l16][quad * 8];
    }
#pragma unroll
    for (int mf = 0; mf < 4; mf++) {
      bfrag ah = *(const bfrag*)&Ah[mf * 16 + l16][quad * 8];
      bfrag al = *(const bfrag*)&Al[mf * 16 + l16][quad * 8];
#pragma unroll
      for (int nf = 0; nf < NF; nf++) {
        acc[mf][nf] = __builtin_amdgcn_mfma_f32_16x16x32_bf16(al, bh[nf], acc[mf][nf], 0, 0, 0);
        acc[mf][nf] = __builtin_amdgcn_mfma_f32_16x16x32_bf16(ah, bl[nf], acc[mf][nf], 0, 0, 0);
        acc[mf][nf] = __builtin_amdgcn_mfma_f32_16x16x32_bf16(ah, bh[nf], acc[mf][nf], 0, 0, 0);
      }
    }
  }
  // epilogue: C/D layout row = quad*4 + r, col = lane&15
#pragma unroll
  for (int mf = 0; mf < 4; mf++) {
#pragma unroll
    for (int nf = 0; nf < NF; nf++) {
      int col = n0 + colb0 + nf * 16 + l16;
      float bi = bias ? bias[col] : 0.f;
#pragma unroll
      for (int r = 0; r < 4; r++) {
        int row = m0 + mf * 16 + quad * 4 + r;
        float o = acc[mf][nf][r] + bi;
        if (ACT == 1) o = gelu_exact(o);
        if (Res) o = o + Res[(long long)row * ldc + col];
        C[(long long)row * ldc + col] = o;
      }
    }
  }
}

extern "C" void kernel_launch(void* const* d_in, const int* in_sizes, int n_in,
                              void* d_out, int out_size, void* d_ws, size_t ws_size,
                              hipStream_t stream) {
  const float* query     = (const float*)d_in[0];
  const float* ln1_g     = (const float*)d_in[1];
  const float* ln1_b     = (const float*)d_in[2];
  const float* in_proj_w = (const float*)d_in[3];
  const float* in_proj_b = (const float*)d_in[4];
  const float* out_w     = (const float*)d_in[5];
  const float* out_b     = (const float*)d_in[6];
  const float* conv_w    = (const float*)d_in[7];
  const float* conv_b    = (const float*)d_in[8];
  const float* ln2_g     = (const float*)d_in[9];
  const float* ln2_b     = (const float*)d_in[10];
  const float* mlp_w1    = (const float*)d_in[11];
  const float* mlp_b1    = (const float*)d_in[12];
  const float* mlp_w2    = (const float*)d_in[13];
  const float* mlp_b2    = (const float*)d_in[14];
  float* out = (float*)d_out;
  char* ws = (char*)d_ws;

  // R7-exact layout: peak 112.25 MiB (proven safe)
  float* nq     = (float*)(ws + 0);                      // 8 MiB
  float* qkv    = (float*)(ws + (8ull << 20));           // 24 MiB
  float* dist   = (float*)(ws + (32ull << 20));          // 128 KiB
  float* invrs  = (float*)(ws + (32ull << 20) + 131072); // 128 KiB
  float* scores = (float*)(ws + (32ull << 20) + 262144); // 16 MiB
  float* ctx    = (float*)(ws + (48ull << 20) + 262144); // 64 MiB -> 112.25 MiB
  float* ln2out = scores;                                // reuse
  float* hbuf   = nq;                                    // reuse nq+qkv (32 MiB)

  // 1. LN1 (frozen)
  ln_np<<<dim3(NB * SQ), 64, 0, stream>>>(query, ln1_g, ln1_b, nq);
  // 2. distances (frozen)
  dist_np<<<dim3(NB * NH, 4), 256, 0, stream>>>(nq, conv_w, conv_b, dist);
  // 3. qkv (frozen chain)  M=4096 N=1536 K=512
  gemm_nt<0, 384><<<dim3(24, 64, 1), 256, 0, stream>>>(nq, EE, 0, in_proj_w, EE, 0,
                                                       in_proj_b, nullptr, qkv, 3 * EE, 0, EE, 1.f);
  // 4. scores (frozen chain + true division)  M=N=1024 K=512, batched B
  gemm_nt<2, 384><<<dim3(16, 16, NB), 256, 0, stream>>>(
      qkv, 3 * EE, (long long)SQ * 3 * EE, qkv + EE, 3 * EE, (long long)SQ * 3 * EE,
      nullptr, nullptr, scores, SQ, (long long)SQ * SQ, EE, sqrtf(512.0f));
  // 5. gated row sums (frozen)
  rowsum_np<<<dim3(SQ, NB * NH), 64, 0, stream>>>(scores, dist, invrs);
  // 6. ctx wide-N nc=4 (proven)  M=1024 N=512 K=1024
  ctx_gemm_w<<<dim3(2, 16, NB * NH), 256, 0, stream>>>(scores, dist, invrs, qkv, ctx);
  // 7. attn_out + residual (MFMA bf16x3)  M=4096 N=512 K=4096
  gemm_bf3<0, 64><<<dim3(8, 64), 256, 0, stream>>>(ctx, NH * EE, out_w, NH * EE,
                                                   out_b, query, out, EE, NH * EE);
  // 8. LN2
  ln_np<<<dim3(NB * SQ), 64, 0, stream>>>(out, ln2_g, ln2_b, ln2out);
  // 9. MLP1 + gelu (MFMA bf16x3)  M=4096 N=2048 K=512
  gemm_bf3<1, 128><<<dim3(16, 64), 256, 0, stream>>>(ln2out, EE, mlp_w1, EE,
                                                     mlp_b1, nullptr, hbuf, 4 * EE, EE);
  // 10. MLP2 + residual (MFMA bf16x3)  M=4096 N=512 K=2048
  gemm_bf3<0, 64><<<dim3(8, 64), 256, 0, stream>>>(hbuf, 4 * EE, mlp_w2, 4 * EE,
                                                   mlp_b2, out, out, EE, 4 * EE);
}